// Round 1
// baseline (955.172 us; speedup 1.0000x reference)
//
#include <hip/hip_runtime.h>
#include <math.h>

#define NUM_CLS 32000
#define BATCH   4096
#define RATIO   1.0f
#define BLOCK   256

// Combine two online-logsumexp states (m, s): lse = m + log(s)
__device__ __forceinline__ void lse_combine(float& m, float& s, float mo, float so) {
    float mn = fmaxf(m, mo);
    // exp(-inf) = 0 handles empty states (s==0, m==-inf) correctly
    s = s * __expf(m - mn) + so * __expf(mo - mn);
    m = mn;
}

__device__ __forceinline__ void argmin_combine(float& v, int& i, float vo, int io) {
    if (vo < v || (vo == v && io < i)) { v = vo; i = io; }
}

__global__ __launch_bounds__(BLOCK) void rce_row_kernel(
    const float* __restrict__ input,
    const float* __restrict__ target,
    float* __restrict__ row_out)
{
    const int b = blockIdx.x;
    const float* in_row = input + (size_t)b * NUM_CLS;
    const float* tg_row = target + (size_t)b * NUM_CLS;
    const float4* in4 = (const float4*)in_row;
    const float4* tg4 = (const float4*)tg_row;
    const int nvec = NUM_CLS / 4; // 8000

    // 4 independent accumulator sets (one per float4 component) to break
    // the online-logsumexp dependence chain.
    float sum[4] = {0.f, 0.f, 0.f, 0.f};
    float m[4]   = {-INFINITY, -INFINITY, -INFINITY, -INFINITY};
    float s[4]   = {0.f, 0.f, 0.f, 0.f};
    float tv[4]  = {INFINITY, INFINITY, INFINITY, INFINITY};
    int   ti[4]  = {0, 0, 0, 0};

    for (int i = threadIdx.x; i < nvec; i += BLOCK) {
        float4 x = in4[i];
        float4 t = tg4[i];
        float xs[4] = {x.x, x.y, x.z, x.w};
        float ts[4] = {t.x, t.y, t.z, t.w};
        #pragma unroll
        for (int k = 0; k < 4; ++k) {
            sum[k] += xs[k];
            float nx = -xs[k];
            float mn = fmaxf(m[k], nx);
            s[k] = s[k] * __expf(m[k] - mn) + __expf(nx - mn);
            m[k] = mn;
            argmin_combine(tv[k], ti[k], ts[k], 4 * i + k);
        }
    }

    // fold 4 component-accumulators into one
    float S = (sum[0] + sum[1]) + (sum[2] + sum[3]);
    float M = m[0], Sc = s[0];
    lse_combine(M, Sc, m[1], s[1]);
    lse_combine(M, Sc, m[2], s[2]);
    lse_combine(M, Sc, m[3], s[3]);
    float TV = tv[0]; int TI = ti[0];
    argmin_combine(TV, TI, tv[1], ti[1]);
    argmin_combine(TV, TI, tv[2], ti[2]);
    argmin_combine(TV, TI, tv[3], ti[3]);

    // wave64 shuffle reduce
    #pragma unroll
    for (int off = 32; off > 0; off >>= 1) {
        S += __shfl_down(S, off);
        float mo = __shfl_down(M, off);
        float so = __shfl_down(Sc, off);
        lse_combine(M, Sc, mo, so);
        float vo = __shfl_down(TV, off);
        int   io = __shfl_down(TI, off);
        argmin_combine(TV, TI, vo, io);
    }

    // cross-wave reduce via LDS (4 waves)
    __shared__ float sm_S[4], sm_M[4], sm_s[4], sm_tv[4];
    __shared__ int sm_ti[4];
    const int wave = threadIdx.x >> 6;
    const int lane = threadIdx.x & 63;
    if (lane == 0) {
        sm_S[wave] = S; sm_M[wave] = M; sm_s[wave] = Sc;
        sm_tv[wave] = TV; sm_ti[wave] = TI;
    }
    __syncthreads();
    if (threadIdx.x == 0) {
        float fS = sm_S[0], fM = sm_M[0], fs = sm_s[0], fTV = sm_tv[0];
        int fTI = sm_ti[0];
        #pragma unroll
        for (int w = 1; w < 4; ++w) {
            fS += sm_S[w];
            lse_combine(fM, fs, sm_M[w], sm_s[w]);
            argmin_combine(fTV, fTI, sm_tv[w], sm_ti[w]);
        }
        float L  = fM + __logf(fs);             // logsumexp(-x) over the row
        float xi = in_row[fTI];                 // input[b, argmin(target[b,:])]
        const float kw = RATIO / (float)(NUM_CLS - 1);
        row_out[b] = kw * (fS + (float)(NUM_CLS - 1) * L - xi);
    }
}

__global__ __launch_bounds__(256) void rce_reduce_kernel(
    const float* __restrict__ row_in, float* __restrict__ out)
{
    float s = 0.f;
    for (int i = threadIdx.x; i < BATCH; i += 256) s += row_in[i];
    #pragma unroll
    for (int off = 32; off > 0; off >>= 1) s += __shfl_down(s, off);
    __shared__ float sm[4];
    const int wave = threadIdx.x >> 6;
    const int lane = threadIdx.x & 63;
    if (lane == 0) sm[wave] = s;
    __syncthreads();
    if (threadIdx.x == 0) {
        out[0] = ((sm[0] + sm[1]) + (sm[2] + sm[3])) * (1.0f / (float)BATCH);
    }
}

extern "C" void kernel_launch(void* const* d_in, const int* in_sizes, int n_in,
                              void* d_out, int out_size, void* d_ws, size_t ws_size,
                              hipStream_t stream) {
    const float* input  = (const float*)d_in[0];
    const float* target = (const float*)d_in[1];
    float* row = (float*)d_ws;   // BATCH floats of scratch
    float* out = (float*)d_out;

    rce_row_kernel<<<BATCH, BLOCK, 0, stream>>>(input, target, row);
    rce_reduce_kernel<<<1, 256, 0, stream>>>(row, out);
}